// Round 1
// baseline (406.798 us; speedup 1.0000x reference)
//
#include <hip/hip_runtime.h>

#define NDIM 128
#define NOBS 16

__device__ __forceinline__ float sigf(float v) { return 1.0f / (1.0f + expf(-v)); }
__device__ __forceinline__ float siluf(float v) { return v * sigf(v); }
__device__ __forceinline__ float dsiluf(float v) {
    float s = sigf(v);
    return s * (1.0f + v * (1.0f - s));
}

// ---------------------------------------------------------------------------
// Kernel 1: per-(batch,agent) row gradient of the H module.
// One block = one row (4096 rows), 128 threads, thread i owns dim i.
// Writes dHdz (512 x 16) into `out` (used as scratch; kernel 2 overwrites).
// ---------------------------------------------------------------------------
__global__ __launch_bounds__(128) void k_hgrad(
    const float* __restrict__ x,
    const float* __restrict__ Win, const float* __restrict__ bin,
    const float* __restrict__ Aq, const float* __restrict__ Ak, const float* __restrict__ Av,
    const float* __restrict__ Bq, const float* __restrict__ Bk, const float* __restrict__ Bv,
    const float* __restrict__ Wout, const float* __restrict__ bout,
    float* __restrict__ dHdz)
{
    const int row = blockIdx.x;    // 0..4095  (= b*8 + agent)
    const int tid = threadIdx.x;   // 0..127

    __shared__ float sx[NOBS];
    __shared__ float sh[NDIM];
    __shared__ float sQ[NDIM], sK[NDIM], sV[NDIM];
    __shared__ double sm[NDIM], sl[NDIM];
    __shared__ float st[NDIM], sz[NDIM], sdt[NDIM];
    __shared__ float sy[25], swp[25], sdwp[25];
    __shared__ float sdQp[NDIM], sdKp[NDIM], sdVp[NDIM], sdhp[NDIM];

    if (tid < NOBS) sx[tid] = x[row * NOBS + tid];
    __syncthreads();

    // ---- forward: h = silu(x @ Win + bin) ----
    double acc = (double)bin[tid];
    for (int o = 0; o < NOBS; ++o)
        acc += (double)sx[o] * (double)Win[o * NDIM + tid];
    const float hp = (float)acc;
    sh[tid] = siluf(hp);
    __syncthreads();

    // ---- forward: Q,K,V = silu(A* h + B*) ----
    double aq = (double)Bq[tid], ak = (double)Bk[tid], av = (double)Bv[tid];
    for (int j = 0; j < NDIM; ++j) {
        const double hj = (double)sh[j];
        aq += (double)Aq[tid * NDIM + j] * hj;
        ak += (double)Ak[tid * NDIM + j] * hj;
        av += (double)Av[tid * NDIM + j] * hj;
    }
    const float Qp = (float)aq, Kp = (float)ak, Vp = (float)av;
    const float Qi = siluf(Qp), Ki = siluf(Kp), Vi = siluf(Vp);
    sQ[tid] = Qi; sK[tid] = Ki; sV[tid] = Vi;
    __syncthreads();

    // ---- forward: softmax attention, s = 1:  A_ij = softmax_j(Q_i * K_j) ----
    double mi = -1e300;
    for (int j = 0; j < NDIM; ++j) {
        const double qk = (double)Qi * (double)sK[j];
        mi = fmax(mi, qk);
    }
    double l = 0.0, tnum = 0.0;
    for (int j = 0; j < NDIM; ++j) {
        const double qk = (double)Qi * (double)sK[j];
        const double e = (double)expf((float)(qk - mi));
        l += e;
        tnum += e * (double)sV[j];
    }
    const float ti = (float)(tnum / l);
    sm[tid] = mi; sl[tid] = l; st[tid] = ti;
    sz[tid] = siluf(ti);
    __syncthreads();

    // ---- forward: y = silu(z @ Wout + bout)  (25 outputs) ----
    if (tid < 25) {
        double a = (double)bout[tid];
        for (int i = 0; i < NDIM; ++i)
            a += (double)sz[i] * (double)Wout[i * 25 + tid];
        const float wp = (float)a;
        swp[tid] = wp;
        sy[tid] = siluf(wp);
    }
    __syncthreads();

    // ---- backward through the quadratic head ----
    // f = m11*(q0^2+q1^2) + (m12+m21)*(q0q2+q1q3) + m22*(q2^2+q3^2) + mpp
    if (tid < 25) {
        float m11 = 0.f, m12 = 0.f, m21 = 0.f, m22 = 0.f;
        for (int k = 0;  k < 5;  ++k) m11 += sy[k] * sy[k];
        for (int k = 5;  k < 10; ++k) m12 += sy[k] * sy[k];
        for (int k = 10; k < 15; ++k) m21 += sy[k] * sy[k];
        for (int k = 15; k < 20; ++k) m22 += sy[k] * sy[k];
        const float q0 = sy[0], q1 = sy[1], q2 = sy[2], q3 = sy[3];
        const float dm11 = q0 * q0 + q1 * q1;
        const float dm12 = q0 * q2 + q1 * q3;   // == dm21
        const float dm22 = q2 * q2 + q3 * q3;
        float dy;
        if      (tid < 5)  dy = 2.0f * sy[tid] * dm11;
        else if (tid < 10) dy = 2.0f * sy[tid] * dm12;
        else if (tid < 15) dy = 2.0f * sy[tid] * dm12;
        else if (tid < 20) dy = 2.0f * sy[tid] * dm22;
        else               dy = 2.0f * sy[tid];          // mpp
        const float ms = m12 + m21;
        if (tid == 0) dy += 2.0f * m11 * q0 + ms * q2;
        if (tid == 1) dy += 2.0f * m11 * q1 + ms * q3;
        if (tid == 2) dy += ms * q0 + 2.0f * m22 * q2;
        if (tid == 3) dy += ms * q1 + 2.0f * m22 * q3;
        sdwp[tid] = dy * dsiluf(swp[tid]);
    }
    __syncthreads();

    // ---- backward: dz = Wout @ dwp ; dt = dz * silu'(t) ----
    {
        double a = 0.0;
        for (int k = 0; k < 25; ++k)
            a += (double)Wout[tid * 25 + k] * (double)sdwp[k];
        sdt[tid] = (float)a * dsiluf(ti);
    }
    __syncthreads();

    // ---- backward through attention ----
    // dQ_i = dt_i * sum_j A_ij K_j (V_j - t_i)
    {
        double a = 0.0;
        const double mown = sm[tid];
        for (int j = 0; j < NDIM; ++j) {
            const double qk = (double)Qi * (double)sK[j];
            const double e = (double)expf((float)(qk - mown));
            a += e * (double)sK[j] * ((double)sV[j] - (double)ti);
        }
        const float dQ = sdt[tid] * (float)(a / sl[tid]);
        sdQp[tid] = dQ * dsiluf(Qp);
    }
    // dV_j = sum_i A_ij dt_i ;  dK_j = sum_i A_ij dt_i Q_i (V_j - t_i)
    {
        double accv = 0.0, acck = 0.0;
        for (int i = 0; i < NDIM; ++i) {
            const double qk = (double)sQ[i] * (double)Ki;
            const double e = (double)expf((float)(qk - sm[i])) / sl[i];
            const double w = e * (double)sdt[i];
            accv += w;
            acck += w * (double)sQ[i] * ((double)Vi - (double)st[i]);
        }
        sdVp[tid] = (float)accv * dsiluf(Vp);
        sdKp[tid] = (float)acck * dsiluf(Kp);
    }
    __syncthreads();

    // ---- backward: dh = Aq^T dQp + Ak^T dKp + Av^T dVp ;  dhp = dh * silu'(hp)
    {
        double a = 0.0;
        for (int i = 0; i < NDIM; ++i) {
            a += (double)Aq[i * NDIM + tid] * (double)sdQp[i];
            a += (double)Ak[i * NDIM + tid] * (double)sdKp[i];
            a += (double)Av[i * NDIM + tid] * (double)sdVp[i];
        }
        sdhp[tid] = (float)a * dsiluf(hp);
    }
    __syncthreads();

    // ---- dx_o = sum_d Win[o,d] dhp_d for o = 0,1 only ----
    if (tid < 2) {
        double a = 0.0;
        for (int d = 0; d < NDIM; ++d)
            a += (double)Win[tid * NDIM + d] * (double)sdhp[d];
        const int b = row >> 3, ag = row & 7;
        // dHdz[b, a]   = g[b,a,0] ;  dHdz[b, 8+a] = g[b,a,1]
        dHdz[b * 16 + tid * 8 + ag] = (float)a;
    }
}

// ---------------------------------------------------------------------------
// Shared forward core for the J / R modules (s = 8 attention), one batch per
// block, 128 threads, thread i owns dim i. Leaves silu(w[s,o]) in sw[s*OUTD+o].
// ---------------------------------------------------------------------------
template <int OUTD>
__device__ void att_feat_fwd(
    const float* __restrict__ xb,   // x[b] : 8 agents x 16 obs
    const float* __restrict__ Win, const float* __restrict__ bin,
    const float* __restrict__ Aq, const float* __restrict__ Ak, const float* __restrict__ Av,
    const float* __restrict__ Bq, const float* __restrict__ Bk, const float* __restrict__ Bv,
    const float* __restrict__ Wout, const float* __restrict__ bout,
    float* sx, float* sht, float* sKk, float* sVv, float* szz, float* sw)
{
    const int tid = threadIdx.x;

    sx[tid] = xb[tid];   // 8*16 = 128
    __syncthreads();

    // ht[d][a] = silu(x[a] . Win[:,d] + bin[d])   (stride 9 to dodge banks)
    {
        double acc[8];
        const double b0 = (double)bin[tid];
        for (int a = 0; a < 8; ++a) acc[a] = b0;
        for (int o = 0; o < NOBS; ++o) {
            const double w = (double)Win[o * NDIM + tid];
            for (int a = 0; a < 8; ++a)
                acc[a] += w * (double)sx[a * NOBS + o];
        }
        for (int a = 0; a < 8; ++a) sht[tid * 9 + a] = siluf((float)acc[a]);
    }
    __syncthreads();

    // Q (registers), K, V (LDS): [i][s]
    float Qs[8];
    {
        double aq[8], ak[8], av[8];
        const double bq = (double)Bq[tid], bk = (double)Bk[tid], bv = (double)Bv[tid];
        for (int s = 0; s < 8; ++s) { aq[s] = bq; ak[s] = bk; av[s] = bv; }
        for (int j = 0; j < NDIM; ++j) {
            const double wq = (double)Aq[tid * NDIM + j];
            const double wk = (double)Ak[tid * NDIM + j];
            const double wv = (double)Av[tid * NDIM + j];
            for (int s = 0; s < 8; ++s) {
                const double hh = (double)sht[j * 9 + s];
                aq[s] += wq * hh; ak[s] += wk * hh; av[s] += wv * hh;
            }
        }
        for (int s = 0; s < 8; ++s) {
            Qs[s] = siluf((float)aq[s]);
            sKk[tid * 9 + s] = siluf((float)ak[s]);
            sVv[tid * 9 + s] = siluf((float)av[s]);
        }
    }
    __syncthreads();

    // attention row i: L_ij = sum_s Q[i,s] K[j,s]; softmax over j; z = silu(A V)
    {
        double Qd[8];
        for (int s = 0; s < 8; ++s) Qd[s] = (double)Qs[s];
        double mi = -1e300;
        for (int j = 0; j < NDIM; ++j) {
            double L = 0.0;
            for (int s = 0; s < 8; ++s) L += Qd[s] * (double)sKk[j * 9 + s];
            mi = fmax(mi, L);
        }
        double l = 0.0, tacc[8];
        for (int s = 0; s < 8; ++s) tacc[s] = 0.0;
        for (int j = 0; j < NDIM; ++j) {
            double L = 0.0;
            for (int s = 0; s < 8; ++s) L += Qd[s] * (double)sKk[j * 9 + s];
            const double e = (double)expf((float)(L - mi));
            l += e;
            for (int s = 0; s < 8; ++s) tacc[s] += e * (double)sVv[j * 9 + s];
        }
        for (int s = 0; s < 8; ++s)
            szz[s * (NDIM + 4) + tid] = siluf((float)(tacc[s] / l));
    }
    __syncthreads();

    // w[s,o] = silu(z[s,:] @ Wout[:,o] + bout[o])
    if (tid < 8 * OUTD) {
        const int s_ = tid / OUTD, o = tid % OUTD;
        double a = (double)bout[o];
        for (int i = 0; i < NDIM; ++i)
            a += (double)szz[s_ * (NDIM + 4) + i] * (double)Wout[i * OUTD + o];
        sw[tid] = siluf((float)a);
    }
    __syncthreads();
}

// ---------------------------------------------------------------------------
// Kernel 2: per-batch J + R modules + final assembly.
// `inout` holds dHdz (written by k_hgrad) on entry; overwritten with u.
// ---------------------------------------------------------------------------
__global__ __launch_bounds__(128) void k_jr(
    const float* __restrict__ x,
    const float* __restrict__ JWin, const float* __restrict__ Jbin,
    const float* __restrict__ JAq, const float* __restrict__ JAk, const float* __restrict__ JAv,
    const float* __restrict__ JBq, const float* __restrict__ JBk, const float* __restrict__ JBv,
    const float* __restrict__ JWout, const float* __restrict__ Jbout,
    const float* __restrict__ RWin, const float* __restrict__ Rbin,
    const float* __restrict__ RAq, const float* __restrict__ RAk, const float* __restrict__ RAv,
    const float* __restrict__ RBq, const float* __restrict__ RBk, const float* __restrict__ RBv,
    const float* __restrict__ RWout, const float* __restrict__ Rbout,
    float* __restrict__ inout)
{
    __shared__ float sx[128];
    __shared__ float sht[NDIM * 9], sKk[NDIM * 9], sVv[NDIM * 9];
    __shared__ float szz[8 * (NDIM + 4)];
    __shared__ float sw[128];
    __shared__ double sdH[16], sg[32], sRm[16][17], srs[16], svv[16];
    __shared__ double sJval;

    const int b = blockIdx.x;
    const int tid = threadIdx.x;

    if (tid < 16) sdH[tid] = (double)inout[b * 16 + tid];
    // (protected by the first __syncthreads() inside att_feat_fwd)

    // ---- J module: s_J(b) = sum of all 64 silu(w) outputs ----
    att_feat_fwd<8>(x + b * 128, JWin, Jbin, JAq, JAk, JAv, JBq, JBk, JBv,
                    JWout, Jbout, sx, sht, sKk, sVv, szz, sw);
    if (tid == 0) {
        double a = 0.0;
        for (int i = 0; i < 64; ++i) a += (double)sw[i];
        sJval = a;
    }
    __syncthreads();

    // ---- R module ----
    att_feat_fwd<16>(x + b * 128, RWin, Rbin, RAq, RAk, RAv, RBq, RBk, RBv,
                     RWout, Rbout, sx, sht, sKk, sVv, szz, sw);

    // g[pq][c] = sum_{o=4*pq..4*pq+3} silu(w[c,o])   (pq = 2*p + q)
    if (tid < 32) {
        const int pq = tid >> 3, c = tid & 7;
        const int base = c * 16 + pq * 4;
        sg[tid] = (double)sw[base] + (double)sw[base + 1]
                + (double)sw[base + 2] + (double)sw[base + 3];
    }
    __syncthreads();

    // Rupper[i][j] = R[i,j]^2 + R[j,i]^2 with R[i,j] = g[(i>>3)*2+(j>>3)][j&7]
    for (int e = tid; e < 256; e += 128) {
        const int i = e >> 4, j = e & 15;
        const double rij = sg[((i >> 3) * 2 + (j >> 3)) * 8 + (j & 7)];
        const double rji = sg[((j >> 3) * 2 + (i >> 3)) * 8 + (i & 7)];
        sRm[i][j] = rij * rij + rji * rji;   // Rupper for now
    }
    __syncthreads();

    if (tid < 16) {   // full row sums of Rupper
        double a = 0.0;
        for (int j = 0; j < 16; ++j) a += sRm[tid][j];
        srs[tid] = a;
    }
    __syncthreads();

    // Rm: diag = row sum, offdiag = -Rupper  (each entry touched by one thread)
    for (int e = tid; e < 256; e += 128) {
        const int i = e >> 4, j = e & 15;
        sRm[i][j] = (i == j) ? srs[i] : -sRm[i][j];
    }
    __syncthreads();

    // S dH = Rm (Rm dH)  (Rm symmetric)
    if (tid < 16) {
        double a = 0.0;
        for (int j = 0; j < 16; ++j) a += sRm[tid][j] * sdH[j];
        svv[tid] = a;
    }
    __syncthreads();

    if (tid < 16) {
        double a = 0.0;
        for (int k = 0; k < 16; ++k) a += sRm[tid][k] * svv[k];
        const double sj = sJval;
        const double jterm = (tid < 8) ? 2.0 * sj * sdH[8 + tid]
                                       : -2.0 * sj * sdH[tid - 8];
        inout[b * 16 + tid] = (float)(jterm - a);
    }
}

// ---------------------------------------------------------------------------
extern "C" void kernel_launch(void* const* d_in, const int* in_sizes, int n_in,
                              void* d_out, int out_size, void* d_ws, size_t ws_size,
                              hipStream_t stream)
{
    const float* x = (const float*)d_in[0];
    float* out = (float*)d_out;

#define ARGS10(base) \
    (const float*)d_in[(base) + 0], (const float*)d_in[(base) + 1], \
    (const float*)d_in[(base) + 2], (const float*)d_in[(base) + 3], \
    (const float*)d_in[(base) + 4], (const float*)d_in[(base) + 5], \
    (const float*)d_in[(base) + 6], (const float*)d_in[(base) + 7], \
    (const float*)d_in[(base) + 8], (const float*)d_in[(base) + 9]

    // H-module gradient: writes dHdz (512x16) into d_out as staging.
    k_hgrad<<<dim3(4096), dim3(128), 0, stream>>>(x, ARGS10(1), out);
    // J + R modules + final assembly: reads dHdz from d_out, overwrites with u.
    k_jr<<<dim3(512), dim3(128), 0, stream>>>(x, ARGS10(11), ARGS10(21), out);
#undef ARGS10
}

// Round 2
// 232.157 us; speedup vs baseline: 1.7523x; 1.7523x over previous
//
#include <hip/hip_runtime.h>

#define NDIM 128
#define NOBS 16

__device__ __forceinline__ float sigf(float v) { return 1.0f / (1.0f + expf(-v)); }
__device__ __forceinline__ float siluf(float v) { return v * sigf(v); }
__device__ __forceinline__ float dsiluf(float v) {
    float s = sigf(v);
    return s * (1.0f + v * (1.0f - s));
}

// ---------------------------------------------------------------------------
// Kernel 1: per-(batch,agent) row gradient of the H module. All f32.
// One block = one row (4096 rows), 128 threads, thread i owns dim i.
// Writes dHdz (512 x 16) into `out` (used as staging; kernel 2 overwrites).
// ---------------------------------------------------------------------------
__global__ __launch_bounds__(128) void k_hgrad(
    const float* __restrict__ x,
    const float* __restrict__ Win, const float* __restrict__ bin,
    const float* __restrict__ Aq, const float* __restrict__ Ak, const float* __restrict__ Av,
    const float* __restrict__ Bq, const float* __restrict__ Bk, const float* __restrict__ Bv,
    const float* __restrict__ Wout, const float* __restrict__ bout,
    float* __restrict__ dHdz)
{
    const int row = blockIdx.x;    // 0..4095  (= b*8 + agent)
    const int tid = threadIdx.x;   // 0..127
    const int wv  = tid >> 6;      // wave id (0/1)

    __shared__ float  sx[NOBS];
    __shared__ float4 sh4[NDIM / 4];   // h packed as float4
    __shared__ float4 sKVV[NDIM];      // {K, V, K*V, -} per j
    __shared__ float  sQ[NDIM];
    __shared__ float4 spz4[NDIM / 4];  // z packed as float4
    __shared__ float4 sC[NDIM];        // {w=dt/l, c1=w*Q, c2=c1*t, m}
    __shared__ float4 sdQKV[NDIM];     // {dQp, dKp, dVp, -}
    __shared__ float  sy[25], swp[25], sdwp[25];
    __shared__ float  sred[4];

    if (tid < NOBS) sx[tid] = x[row * NOBS + tid];
    __syncthreads();

    // ---- forward: h = silu(x @ Win + bin) ----
    float hacc = bin[tid];
    #pragma unroll
    for (int o = 0; o < NOBS; ++o)
        hacc = fmaf(Win[o * NDIM + tid], sx[o], hacc);
    const float hp = hacc;
    ((float*)sh4)[tid] = siluf(hp);
    __syncthreads();

    // ---- forward: Q,K,V = silu(A* h + B*) ---- (float4 row streams)
    float aq = Bq[tid], ak = Bk[tid], av = Bv[tid];
    {
        const float4* Aq4 = (const float4*)(Aq + tid * NDIM);
        const float4* Ak4 = (const float4*)(Ak + tid * NDIM);
        const float4* Av4 = (const float4*)(Av + tid * NDIM);
        #pragma unroll 4
        for (int c = 0; c < NDIM / 4; ++c) {
            const float4 h4 = sh4[c];
            const float4 wq = Aq4[c], wk = Ak4[c], wvv = Av4[c];
            aq = fmaf(wq.x, h4.x, aq); aq = fmaf(wq.y, h4.y, aq);
            aq = fmaf(wq.z, h4.z, aq); aq = fmaf(wq.w, h4.w, aq);
            ak = fmaf(wk.x, h4.x, ak); ak = fmaf(wk.y, h4.y, ak);
            ak = fmaf(wk.z, h4.z, ak); ak = fmaf(wk.w, h4.w, ak);
            av = fmaf(wvv.x, h4.x, av); av = fmaf(wvv.y, h4.y, av);
            av = fmaf(wvv.z, h4.z, av); av = fmaf(wvv.w, h4.w, av);
        }
    }
    const float Qp = aq, Kp = ak, Vp = av;
    const float Qi = siluf(Qp), Ki = siluf(Kp), Vi = siluf(Vp);
    sQ[tid] = Qi;
    sKVV[tid] = make_float4(Ki, Vi, Ki * Vi, 0.0f);

    // wave-level max/min of K (for row-max m_i = max(Qi*maxK, Qi*minK))
    {
        float kmax = Ki, kmin = Ki;
        #pragma unroll
        for (int off = 32; off; off >>= 1) {
            kmax = fmaxf(kmax, __shfl_xor(kmax, off));
            kmin = fminf(kmin, __shfl_xor(kmin, off));
        }
        if ((tid & 63) == 0) { sred[wv * 2] = kmax; sred[wv * 2 + 1] = kmin; }
    }
    __syncthreads();

    // ---- forward softmax pass + dQ-pass fold ----
    const float kmax = fmaxf(sred[0], sred[2]);
    const float kmin = fminf(sred[1], sred[3]);
    const float mi = fmaxf(Qi * kmax, Qi * kmin);
    float l = 0.f, tn = 0.f, sk = 0.f, skv = 0.f;
    #pragma unroll 4
    for (int j = 0; j < NDIM; ++j) {
        const float4 kv = sKVV[j];
        const float e = expf(fmaf(Qi, kv.x, -mi));
        l += e;
        tn  = fmaf(e, kv.y, tn);
        sk  = fmaf(e, kv.x, sk);
        skv = fmaf(e, kv.z, skv);
    }
    const float rl = 1.0f / l;
    const float ti = tn * rl;
    ((float*)spz4)[tid] = siluf(ti);
    __syncthreads();

    // ---- forward: y = silu(z @ Wout + bout)  (25 outputs) ----
    if (tid < 25) {
        float a = bout[tid];
        for (int c = 0; c < NDIM / 4; ++c) {
            const float4 z4 = spz4[c];
            a = fmaf(z4.x, Wout[(4 * c + 0) * 25 + tid], a);
            a = fmaf(z4.y, Wout[(4 * c + 1) * 25 + tid], a);
            a = fmaf(z4.z, Wout[(4 * c + 2) * 25 + tid], a);
            a = fmaf(z4.w, Wout[(4 * c + 3) * 25 + tid], a);
        }
        swp[tid] = a;
        sy[tid] = siluf(a);
    }
    __syncthreads();

    // ---- backward through the quadratic head ----
    if (tid < 25) {
        float m11 = 0.f, m12 = 0.f, m21 = 0.f, m22 = 0.f;
        for (int k = 0;  k < 5;  ++k) m11 += sy[k] * sy[k];
        for (int k = 5;  k < 10; ++k) m12 += sy[k] * sy[k];
        for (int k = 10; k < 15; ++k) m21 += sy[k] * sy[k];
        for (int k = 15; k < 20; ++k) m22 += sy[k] * sy[k];
        const float q0 = sy[0], q1 = sy[1], q2 = sy[2], q3 = sy[3];
        const float dm11 = q0 * q0 + q1 * q1;
        const float dm12 = q0 * q2 + q1 * q3;
        const float dm22 = q2 * q2 + q3 * q3;
        float dy;
        if      (tid < 5)  dy = 2.0f * sy[tid] * dm11;
        else if (tid < 15) dy = 2.0f * sy[tid] * dm12;
        else if (tid < 20) dy = 2.0f * sy[tid] * dm22;
        else               dy = 2.0f * sy[tid];
        const float ms = m12 + m21;
        if (tid == 0) dy += 2.0f * m11 * q0 + ms * q2;
        if (tid == 1) dy += 2.0f * m11 * q1 + ms * q3;
        if (tid == 2) dy += ms * q0 + 2.0f * m22 * q2;
        if (tid == 3) dy += ms * q1 + 2.0f * m22 * q3;
        sdwp[tid] = dy * dsiluf(swp[tid]);
    }
    __syncthreads();

    // ---- backward: dt_i, then closed-form dQ, pack coefficients ----
    float dQp_;
    {
        float a = 0.f;
        const float* wrow = Wout + tid * 25;
        #pragma unroll
        for (int k = 0; k < 25; ++k) a = fmaf(wrow[k], sdwp[k], a);
        const float dt = a * dsiluf(ti);
        const float w = dt * rl;
        // dQ_i = dt/l * (skv - t*sk)
        dQp_ = (w * fmaf(-ti, sk, skv)) * dsiluf(Qp);
        const float c1 = w * Qi;
        sC[tid] = make_float4(w, c1, c1 * ti, mi);
    }
    __syncthreads();

    // ---- backward dK_j / dV_j: one pass over i ----
    {
        float accv = 0.f, acck1 = 0.f, acck2 = 0.f;
        #pragma unroll 4
        for (int i = 0; i < NDIM; ++i) {
            const float4 c = sC[i];
            const float e = expf(fmaf(sQ[i], Ki, -c.w));
            accv  = fmaf(e, c.x, accv);
            acck1 = fmaf(e, c.y, acck1);
            acck2 = fmaf(e, c.z, acck2);
        }
        const float dVp_ = accv * dsiluf(Vp);
        const float dKp_ = fmaf(Vi, acck1, -acck2) * dsiluf(Kp);
        sdQKV[tid] = make_float4(dQp_, dKp_, dVp_, 0.0f);
    }
    __syncthreads();

    // ---- backward: dh_d = sum_i Aq[i][d] dQp_i + Ak[i][d] dKp_i + Av[i][d] dVp_i
    float dhp;
    {
        float a = 0.f;
        #pragma unroll 4
        for (int i = 0; i < NDIM; ++i) {
            const float4 d = sdQKV[i];
            a = fmaf(Aq[i * NDIM + tid], d.x, a);
            a = fmaf(Ak[i * NDIM + tid], d.y, a);
            a = fmaf(Av[i * NDIM + tid], d.z, a);
        }
        dhp = a * dsiluf(hp);
    }
    __syncthreads();   // protects sred reuse

    // ---- dx_o = sum_d Win[o,d] dhp_d, o = 0,1 : wave-shuffle reduce ----
    {
        float t0 = Win[tid] * dhp;          // o = 0
        float t1 = Win[NDIM + tid] * dhp;   // o = 1
        #pragma unroll
        for (int off = 32; off; off >>= 1) {
            t0 += __shfl_xor(t0, off);
            t1 += __shfl_xor(t1, off);
        }
        if ((tid & 63) == 0) { sred[wv * 2] = t0; sred[wv * 2 + 1] = t1; }
    }
    __syncthreads();
    if (tid == 0) {
        const int b = row >> 3, ag = row & 7;
        dHdz[b * 16 + ag]     = sred[0] + sred[2];
        dHdz[b * 16 + 8 + ag] = sred[1] + sred[3];
    }
}

// ---------------------------------------------------------------------------
// J/R forward core (s = 8 attention), 256 threads: tg = tid>>7 splits agents
// in the matvec stages and the j-range in the attention stage.
// Leaves silu(w[s*OUTD+o]) in sw.
// ---------------------------------------------------------------------------
template <int OUTD>
__device__ __forceinline__ void att_feat_fwd(
    const float* __restrict__ Win, const float* __restrict__ bin,
    const float* __restrict__ Aq, const float* __restrict__ Ak, const float* __restrict__ Av,
    const float* __restrict__ Bq, const float* __restrict__ Bk, const float* __restrict__ Bv,
    const float* __restrict__ Wout, const float* __restrict__ bout,
    const float* sx, float (*sh)[132],
    float4 (*sQ4)[132], float4 (*sK4)[132], float4 (*sV4)[132],
    float (*spm)[128], float (*spl)[128], float (*stacc)[2][128],
    float (*szz)[132], float* sw)
{
    const int tid = threadIdx.x;
    const int tl = tid & 127, tg = tid >> 7;
    const int a0 = tg * 4;

    // ---- h[a][d] = silu(x[a] . Win[:,d] + bin[d]) ----
    {
        float acc[4];
        const float b0 = bin[tl];
        #pragma unroll
        for (int r = 0; r < 4; ++r) acc[r] = b0;
        #pragma unroll
        for (int o = 0; o < NOBS; ++o) {
            const float w = Win[o * NDIM + tl];
            #pragma unroll
            for (int r = 0; r < 4; ++r)
                acc[r] = fmaf(w, sx[(a0 + r) * NOBS + o], acc[r]);
        }
        #pragma unroll
        for (int r = 0; r < 4; ++r) sh[a0 + r][tl] = siluf(acc[r]);
    }
    __syncthreads();

    // ---- Q,K,V[d][s] = silu(A. h + B.) : 4 agents per thread-half ----
    {
        float aq[4], ak[4], av[4];
        const float bq = Bq[tl], bk = Bk[tl], bv = Bv[tl];
        #pragma unroll
        for (int r = 0; r < 4; ++r) { aq[r] = bq; ak[r] = bk; av[r] = bv; }
        const float4* Aq4 = (const float4*)(Aq + tl * NDIM);
        const float4* Ak4 = (const float4*)(Ak + tl * NDIM);
        const float4* Av4 = (const float4*)(Av + tl * NDIM);
        #pragma unroll 2
        for (int c = 0; c < NDIM / 4; ++c) {
            const float4 wq = Aq4[c], wk = Ak4[c], wv = Av4[c];
            #pragma unroll
            for (int r = 0; r < 4; ++r) {
                const float4 h4 = *(const float4*)&sh[a0 + r][4 * c];
                aq[r] = fmaf(wq.x, h4.x, aq[r]); aq[r] = fmaf(wq.y, h4.y, aq[r]);
                aq[r] = fmaf(wq.z, h4.z, aq[r]); aq[r] = fmaf(wq.w, h4.w, aq[r]);
                ak[r] = fmaf(wk.x, h4.x, ak[r]); ak[r] = fmaf(wk.y, h4.y, ak[r]);
                ak[r] = fmaf(wk.z, h4.z, ak[r]); ak[r] = fmaf(wk.w, h4.w, ak[r]);
                av[r] = fmaf(wv.x, h4.x, av[r]); av[r] = fmaf(wv.y, h4.y, av[r]);
                av[r] = fmaf(wv.z, h4.z, av[r]); av[r] = fmaf(wv.w, h4.w, av[r]);
            }
        }
        sQ4[tg][tl] = make_float4(siluf(aq[0]), siluf(aq[1]), siluf(aq[2]), siluf(aq[3]));
        sK4[tg][tl] = make_float4(siluf(ak[0]), siluf(ak[1]), siluf(ak[2]), siluf(ak[3]));
        sV4[tg][tl] = make_float4(siluf(av[0]), siluf(av[1]), siluf(av[2]), siluf(av[3]));
    }
    __syncthreads();

    // ---- attention row i = tl over j-half tg: partial softmax ----
    {
        const float4 q0 = sQ4[0][tl], q1 = sQ4[1][tl];
        const int jbeg = tg * 64, jend = jbeg + 64;
        float m = -1e30f;
        for (int j = jbeg; j < jend; ++j) {
            const float4 k0 = sK4[0][j], k1 = sK4[1][j];
            float d = q0.x * k0.x;
            d = fmaf(q0.y, k0.y, d); d = fmaf(q0.z, k0.z, d); d = fmaf(q0.w, k0.w, d);
            d = fmaf(q1.x, k1.x, d); d = fmaf(q1.y, k1.y, d);
            d = fmaf(q1.z, k1.z, d); d = fmaf(q1.w, k1.w, d);
            m = fmaxf(m, d);
        }
        float l = 0.f, t0 = 0.f, t1 = 0.f, t2 = 0.f, t3 = 0.f,
              t4 = 0.f, t5 = 0.f, t6 = 0.f, t7 = 0.f;
        for (int j = jbeg; j < jend; ++j) {
            const float4 k0 = sK4[0][j], k1 = sK4[1][j];
            float d = q0.x * k0.x;
            d = fmaf(q0.y, k0.y, d); d = fmaf(q0.z, k0.z, d); d = fmaf(q0.w, k0.w, d);
            d = fmaf(q1.x, k1.x, d); d = fmaf(q1.y, k1.y, d);
            d = fmaf(q1.z, k1.z, d); d = fmaf(q1.w, k1.w, d);
            const float e = expf(d - m);
            const float4 v0 = sV4[0][j], v1 = sV4[1][j];
            l += e;
            t0 = fmaf(e, v0.x, t0); t1 = fmaf(e, v0.y, t1);
            t2 = fmaf(e, v0.z, t2); t3 = fmaf(e, v0.w, t3);
            t4 = fmaf(e, v1.x, t4); t5 = fmaf(e, v1.y, t5);
            t6 = fmaf(e, v1.z, t6); t7 = fmaf(e, v1.w, t7);
        }
        spm[tg][tl] = m; spl[tg][tl] = l;
        stacc[0][tg][tl] = t0; stacc[1][tg][tl] = t1;
        stacc[2][tg][tl] = t2; stacc[3][tg][tl] = t3;
        stacc[4][tg][tl] = t4; stacc[5][tg][tl] = t5;
        stacc[6][tg][tl] = t6; stacc[7][tg][tl] = t7;
    }
    __syncthreads();

    // ---- merge the two j-halves, z = silu(t) ----
    if (tid < NDIM) {
        const int i = tid;
        const float m0 = spm[0][i], m1 = spm[1][i];
        const float m = fmaxf(m0, m1);
        const float f0 = expf(m0 - m), f1 = expf(m1 - m);
        const float l = spl[0][i] * f0 + spl[1][i] * f1;
        const float rli = 1.0f / l;
        #pragma unroll
        for (int s = 0; s < 8; ++s) {
            const float t = (stacc[s][0][i] * f0 + stacc[s][1][i] * f1) * rli;
            szz[s][i] = siluf(t);
        }
    }
    __syncthreads();

    // ---- w[s,o] = silu(z[s,:] @ Wout[:,o] + bout[o]) ----
    if (tid < 8 * OUTD) {
        const int s = tid / OUTD, o = tid % OUTD;
        float a = bout[o];
        for (int c = 0; c < NDIM / 4; ++c) {
            const float4 z4 = *(const float4*)&szz[s][4 * c];
            a = fmaf(z4.x, Wout[(4 * c + 0) * OUTD + o], a);
            a = fmaf(z4.y, Wout[(4 * c + 1) * OUTD + o], a);
            a = fmaf(z4.z, Wout[(4 * c + 2) * OUTD + o], a);
            a = fmaf(z4.w, Wout[(4 * c + 3) * OUTD + o], a);
        }
        sw[tid] = siluf(a);
    }
    __syncthreads();
}

// ---------------------------------------------------------------------------
// Kernel 2: per-batch J + R modules + final assembly. 256 threads.
// `inout` holds dHdz on entry; overwritten with u.
// ---------------------------------------------------------------------------
__global__ __launch_bounds__(256) void k_jr(
    const float* __restrict__ x,
    const float* __restrict__ JWin, const float* __restrict__ Jbin,
    const float* __restrict__ JAq, const float* __restrict__ JAk, const float* __restrict__ JAv,
    const float* __restrict__ JBq, const float* __restrict__ JBk, const float* __restrict__ JBv,
    const float* __restrict__ JWout, const float* __restrict__ Jbout,
    const float* __restrict__ RWin, const float* __restrict__ Rbin,
    const float* __restrict__ RAq, const float* __restrict__ RAk, const float* __restrict__ RAv,
    const float* __restrict__ RBq, const float* __restrict__ RBk, const float* __restrict__ RBv,
    const float* __restrict__ RWout, const float* __restrict__ Rbout,
    float* __restrict__ inout)
{
    __shared__ float  sx[128];
    __shared__ float  sh[8][132];
    __shared__ float4 sQ4[2][132], sK4[2][132], sV4[2][132];
    __shared__ float  spm[2][128], spl[2][128];
    __shared__ float  stacc[8][2][128];
    __shared__ float  szz[8][132];
    __shared__ float  sw[128];
    __shared__ float  sJv;
    __shared__ double sdH[16], sg[32], sRm[16][17], srs[16], svv[16];

    const int b = blockIdx.x;
    const int tid = threadIdx.x;

    if (tid < 128) sx[tid] = x[b * 128 + tid];
    if (tid >= 128 && tid < 144) sdH[tid - 128] = (double)inout[b * 16 + (tid - 128)];
    __syncthreads();

    // ---- J module ----
    att_feat_fwd<8>(JWin, Jbin, JAq, JAk, JAv, JBq, JBk, JBv, JWout, Jbout,
                    sx, sh, sQ4, sK4, sV4, spm, spl, stacc, szz, sw);
    if (tid < 64) {
        float v = sw[tid];
        #pragma unroll
        for (int off = 32; off; off >>= 1) v += __shfl_xor(v, off);
        if (tid == 0) sJv = v;
    }
    __syncthreads();

    // ---- R module ----
    att_feat_fwd<16>(RWin, Rbin, RAq, RAk, RAv, RBq, RBk, RBv, RWout, Rbout,
                     sx, sh, sQ4, sK4, sV4, spm, spl, stacc, szz, sw);

    // g[pq*8+c] = sum_{o=4pq..4pq+3} w[c*16+o]
    if (tid < 32) {
        const int pq = tid >> 3, c = tid & 7;
        const int base = c * 16 + pq * 4;
        sg[tid] = (double)sw[base] + (double)sw[base + 1]
                + (double)sw[base + 2] + (double)sw[base + 3];
    }
    __syncthreads();

    // Rupper[i][j] = R[i,j]^2 + R[j,i]^2, R[i,j] = g[(i>>3)*2+(j>>3)][j&7]
    {
        const int i = tid >> 4, j = tid & 15;
        const double rij = sg[((i >> 3) * 2 + (j >> 3)) * 8 + (j & 7)];
        const double rji = sg[((j >> 3) * 2 + (i >> 3)) * 8 + (i & 7)];
        sRm[i][j] = rij * rij + rji * rji;
    }
    __syncthreads();

    if (tid < 16) {
        double a = 0.0;
        for (int j = 0; j < 16; ++j) a += sRm[tid][j];
        srs[tid] = a;
    }
    __syncthreads();

    {
        const int i = tid >> 4, j = tid & 15;
        const double v = (i == j) ? srs[i] : -sRm[i][j];
        __syncthreads();
        sRm[i][j] = v;
    }
    __syncthreads();

    if (tid < 16) {
        double a = 0.0;
        for (int j = 0; j < 16; ++j) a += sRm[tid][j] * sdH[j];
        svv[tid] = a;
    }
    __syncthreads();

    if (tid < 16) {
        double a = 0.0;
        for (int k = 0; k < 16; ++k) a += sRm[tid][k] * svv[k];
        const double sj = (double)sJv;
        const double jterm = (tid < 8) ? 2.0 * sj * sdH[8 + tid]
                                       : -2.0 * sj * sdH[tid - 8];
        inout[b * 16 + tid] = (float)(jterm - a);
    }
}

// ---------------------------------------------------------------------------
extern "C" void kernel_launch(void* const* d_in, const int* in_sizes, int n_in,
                              void* d_out, int out_size, void* d_ws, size_t ws_size,
                              hipStream_t stream)
{
    const float* x = (const float*)d_in[0];
    float* out = (float*)d_out;

#define ARGS10(base) \
    (const float*)d_in[(base) + 0], (const float*)d_in[(base) + 1], \
    (const float*)d_in[(base) + 2], (const float*)d_in[(base) + 3], \
    (const float*)d_in[(base) + 4], (const float*)d_in[(base) + 5], \
    (const float*)d_in[(base) + 6], (const float*)d_in[(base) + 7], \
    (const float*)d_in[(base) + 8], (const float*)d_in[(base) + 9]

    k_hgrad<<<dim3(4096), dim3(128), 0, stream>>>(x, ARGS10(1), out);
    k_jr<<<dim3(512), dim3(256), 0, stream>>>(x, ARGS10(11), ARGS10(21), out);
#undef ARGS10
}

// Round 3
// 167.188 us; speedup vs baseline: 2.4332x; 1.3886x over previous
//
#include <hip/hip_runtime.h>

#define NDIM 128
#define NOBS 16

__device__ __forceinline__ float frcp(float x) { return __builtin_amdgcn_rcpf(x); }
__device__ __forceinline__ float fexp(float x) { return __expf(x); }
__device__ __forceinline__ float sigf(float v) { return frcp(1.0f + fexp(-v)); }
__device__ __forceinline__ float siluf(float v) { return v * sigf(v); }
__device__ __forceinline__ float dsiluf(float v) {
    float s = sigf(v);
    return s * (1.0f + v * (1.0f - s));
}

// ---------------------------------------------------------------------------
// Kernel 1: H-module gradient. One block = one BATCH (8 rows), 256 threads.
// tl = tid&127 owns dim tl; tg = tid>>7 owns rows 4*tg .. 4*tg+3.
// Weight streams amortized over 4 rows (12 FMA per loaded float).
// Writes dHdz (512 x 16) into `dHdz` (d_out staging; kernel 2 overwrites).
// ---------------------------------------------------------------------------
__global__ __launch_bounds__(256) void k_hgrad(
    const float* __restrict__ x,
    const float* __restrict__ Win, const float* __restrict__ bin,
    const float* __restrict__ Aq, const float* __restrict__ Ak, const float* __restrict__ Av,
    const float* __restrict__ Bq, const float* __restrict__ Bk, const float* __restrict__ Bv,
    const float* __restrict__ Wout, const float* __restrict__ bout,
    float* __restrict__ dHdz)
{
    const int b   = blockIdx.x;    // batch
    const int tid = threadIdx.x;   // 0..255
    const int tl  = tid & 127;     // dim
    const int tg  = tid >> 7;      // row-half
    const int wid = tid >> 6;      // wave 0..3
    const int r0  = tg * 4;

    __shared__ float  sx[8][NOBS];
    __shared__ float  sh[8][NDIM];
    __shared__ float4 sKVQ[8][NDIM];   // {K, V, K*V, Q}
    __shared__ float  sz[8][NDIM];
    __shared__ float4 sC[8][NDIM];     // {w*e^-m, w*Q*e^-m, w*Q*t*e^-m, Q}
    __shared__ float4 sD[8][NDIM];     // {dQp, dKp, dVp, 0}
    __shared__ float  sy[8][28], swp[8][28], sdwp[8][28];
    __shared__ float  skmax[4][4], skmin[4][4];
    __shared__ float  sred[4][4][2];

    if (tid < 128) sx[tid >> 4][tid & 15] = x[b * 128 + tid];
    __syncthreads();

    // ---- forward: h[r] = silu(x[r] @ Win + bin) ----
    float hp[4];
    {
        float acc[4];
        const float b0 = bin[tl];
        #pragma unroll
        for (int r = 0; r < 4; ++r) acc[r] = b0;
        #pragma unroll
        for (int o = 0; o < NOBS; ++o) {
            const float w = Win[o * NDIM + tl];
            #pragma unroll
            for (int r = 0; r < 4; ++r) acc[r] = fmaf(w, sx[r0 + r][o], acc[r]);
        }
        #pragma unroll
        for (int r = 0; r < 4; ++r) { hp[r] = acc[r]; sh[r0 + r][tl] = siluf(acc[r]); }
    }
    __syncthreads();

    // ---- forward: Q,K,V = silu(A h + B), 4 rows per weight load ----
    float Qp[4], Kp[4], Vp[4], Qv[4], Kv[4], Vv[4];
    {
        float aq[4], ak[4], av[4];
        const float bq = Bq[tl], bk = Bk[tl], bv = Bv[tl];
        #pragma unroll
        for (int r = 0; r < 4; ++r) { aq[r] = bq; ak[r] = bk; av[r] = bv; }
        const float4* Aq4 = (const float4*)(Aq + tl * NDIM);
        const float4* Ak4 = (const float4*)(Ak + tl * NDIM);
        const float4* Av4 = (const float4*)(Av + tl * NDIM);
        #pragma unroll 2
        for (int c = 0; c < NDIM / 4; ++c) {
            const float4 wq = Aq4[c], wk = Ak4[c], wv = Av4[c];
            #pragma unroll
            for (int r = 0; r < 4; ++r) {
                const float4 h4 = *(const float4*)&sh[r0 + r][4 * c];
                aq[r] = fmaf(wq.x, h4.x, aq[r]); aq[r] = fmaf(wq.y, h4.y, aq[r]);
                aq[r] = fmaf(wq.z, h4.z, aq[r]); aq[r] = fmaf(wq.w, h4.w, aq[r]);
                ak[r] = fmaf(wk.x, h4.x, ak[r]); ak[r] = fmaf(wk.y, h4.y, ak[r]);
                ak[r] = fmaf(wk.z, h4.z, ak[r]); ak[r] = fmaf(wk.w, h4.w, ak[r]);
                av[r] = fmaf(wv.x, h4.x, av[r]); av[r] = fmaf(wv.y, h4.y, av[r]);
                av[r] = fmaf(wv.z, h4.z, av[r]); av[r] = fmaf(wv.w, h4.w, av[r]);
            }
        }
        float kmx[4], kmn[4];
        #pragma unroll
        for (int r = 0; r < 4; ++r) {
            Qp[r] = aq[r]; Kp[r] = ak[r]; Vp[r] = av[r];
            Qv[r] = siluf(aq[r]); Kv[r] = siluf(ak[r]); Vv[r] = siluf(av[r]);
            sKVQ[r0 + r][tl] = make_float4(Kv[r], Vv[r], Kv[r] * Vv[r], Qv[r]);
            kmx[r] = Kv[r]; kmn[r] = Kv[r];
        }
        #pragma unroll
        for (int off = 32; off; off >>= 1) {
            #pragma unroll
            for (int r = 0; r < 4; ++r) {
                kmx[r] = fmaxf(kmx[r], __shfl_xor(kmx[r], off));
                kmn[r] = fminf(kmn[r], __shfl_xor(kmn[r], off));
            }
        }
        if ((tid & 63) == 0) {
            #pragma unroll
            for (int r = 0; r < 4; ++r) { skmax[wid][r] = kmx[r]; skmin[wid][r] = kmn[r]; }
        }
    }
    __syncthreads();

    // ---- forward softmax (+ dQ sums folded): row r, query-dim i = tl ----
    float mi[4], rl[4], ti[4], sk[4], skv[4];
    {
        float l[4], tn[4];
        #pragma unroll
        for (int r = 0; r < 4; ++r) {
            const float kx = fmaxf(skmax[2 * tg][r], skmax[2 * tg + 1][r]);
            const float kn = fminf(skmin[2 * tg][r], skmin[2 * tg + 1][r]);
            mi[r] = fmaxf(Qv[r] * kx, Qv[r] * kn);
            l[r] = 0.f; tn[r] = 0.f; sk[r] = 0.f; skv[r] = 0.f;
        }
        #pragma unroll 2
        for (int j = 0; j < NDIM; ++j) {
            #pragma unroll
            for (int r = 0; r < 4; ++r) {
                const float4 kv4 = sKVQ[r0 + r][j];
                const float e = fexp(fmaf(Qv[r], kv4.x, -mi[r]));
                l[r] += e;
                tn[r]  = fmaf(e, kv4.y, tn[r]);
                sk[r]  = fmaf(e, kv4.x, sk[r]);
                skv[r] = fmaf(e, kv4.z, skv[r]);
            }
        }
        #pragma unroll
        for (int r = 0; r < 4; ++r) {
            rl[r] = frcp(l[r]);
            ti[r] = tn[r] * rl[r];
            sz[r0 + r][tl] = siluf(ti[r]);
        }
    }
    __syncthreads();

    // ---- forward: y[r] = silu(z[r] @ Wout + bout), 8x25 tasks ----
    if (tid < 200) {
        const int r = tid / 25, o = tid - 25 * (tid / 25);
        float a = bout[o];
        #pragma unroll 8
        for (int c = 0; c < NDIM / 4; ++c) {
            const float4 z4 = *(const float4*)&sz[r][4 * c];
            a = fmaf(z4.x, Wout[(4 * c + 0) * 25 + o], a);
            a = fmaf(z4.y, Wout[(4 * c + 1) * 25 + o], a);
            a = fmaf(z4.z, Wout[(4 * c + 2) * 25 + o], a);
            a = fmaf(z4.w, Wout[(4 * c + 3) * 25 + o], a);
        }
        swp[r][o] = a;
        sy[r][o] = siluf(a);
    }
    __syncthreads();

    // ---- backward through the quadratic head ----
    if (tid < 200) {
        const int r = tid / 25, o = tid - 25 * (tid / 25);
        float m11 = 0.f, m12 = 0.f, m21 = 0.f, m22 = 0.f;
        for (int k = 0;  k < 5;  ++k) m11 += sy[r][k] * sy[r][k];
        for (int k = 5;  k < 10; ++k) m12 += sy[r][k] * sy[r][k];
        for (int k = 10; k < 15; ++k) m21 += sy[r][k] * sy[r][k];
        for (int k = 15; k < 20; ++k) m22 += sy[r][k] * sy[r][k];
        const float q0 = sy[r][0], q1 = sy[r][1], q2 = sy[r][2], q3 = sy[r][3];
        const float dm11 = q0 * q0 + q1 * q1;
        const float dm12 = q0 * q2 + q1 * q3;
        const float dm22 = q2 * q2 + q3 * q3;
        float dy;
        if      (o < 5)  dy = 2.0f * sy[r][o] * dm11;
        else if (o < 15) dy = 2.0f * sy[r][o] * dm12;
        else if (o < 20) dy = 2.0f * sy[r][o] * dm22;
        else             dy = 2.0f * sy[r][o];
        const float ms = m12 + m21;
        if (o == 0) dy += 2.0f * m11 * q0 + ms * q2;
        if (o == 1) dy += 2.0f * m11 * q1 + ms * q3;
        if (o == 2) dy += ms * q0 + 2.0f * m22 * q2;
        if (o == 3) dy += ms * q1 + 2.0f * m22 * q3;
        sdwp[r][o] = dy * dsiluf(swp[r][o]);
    }
    __syncthreads();

    // ---- backward: dt, closed-form dQ, coefficient pack (e^-m folded) ----
    float dQp_[4];
    {
        float wr[25];
        #pragma unroll
        for (int k = 0; k < 25; ++k) wr[k] = Wout[tl * 25 + k];
        float dt[4] = {0.f, 0.f, 0.f, 0.f};
        #pragma unroll
        for (int k = 0; k < 25; ++k) {
            #pragma unroll
            for (int r = 0; r < 4; ++r)
                dt[r] = fmaf(wr[k], sdwp[r0 + r][k], dt[r]);
        }
        #pragma unroll
        for (int r = 0; r < 4; ++r) {
            dt[r] *= dsiluf(ti[r]);
            const float w = dt[r] * rl[r];
            dQp_[r] = (w * fmaf(-ti[r], sk[r], skv[r])) * dsiluf(Qp[r]);
            const float em = fexp(-mi[r]);
            const float wt = w * em;
            const float c1 = wt * Qv[r];
            sC[r0 + r][tl] = make_float4(wt, c1, c1 * ti[r], Qv[r]);
        }
    }
    __syncthreads();

    // ---- backward dK_j / dV_j: e = exp(Q_i K_j), coeffs carry e^-m_i ----
    {
        float accv[4] = {0.f, 0.f, 0.f, 0.f};
        float k1[4] = {0.f, 0.f, 0.f, 0.f};
        float k2[4] = {0.f, 0.f, 0.f, 0.f};
        #pragma unroll 2
        for (int i = 0; i < NDIM; ++i) {
            #pragma unroll
            for (int r = 0; r < 4; ++r) {
                const float4 c4 = sC[r0 + r][i];
                const float e = fexp(c4.w * Kv[r]);
                accv[r] = fmaf(e, c4.x, accv[r]);
                k1[r]   = fmaf(e, c4.y, k1[r]);
                k2[r]   = fmaf(e, c4.z, k2[r]);
            }
        }
        #pragma unroll
        for (int r = 0; r < 4; ++r) {
            const float dVp_ = accv[r] * dsiluf(Vp[r]);
            const float dKp_ = fmaf(Vv[r], k1[r], -k2[r]) * dsiluf(Kp[r]);
            sD[r0 + r][tl] = make_float4(dQp_[r], dKp_, dVp_, 0.f);
        }
    }
    __syncthreads();

    // ---- backward: dh_d = sum_i Aq[i][d]dQp + Ak[i][d]dKp + Av[i][d]dVp ----
    float dhp[4];
    {
        float acc[4] = {0.f, 0.f, 0.f, 0.f};
        #pragma unroll 4
        for (int i = 0; i < NDIM; ++i) {
            const float aqv = Aq[i * NDIM + tl];
            const float akv = Ak[i * NDIM + tl];
            const float avv = Av[i * NDIM + tl];
            #pragma unroll
            for (int r = 0; r < 4; ++r) {
                const float4 d4 = sD[r0 + r][i];
                acc[r] = fmaf(aqv, d4.x, acc[r]);
                acc[r] = fmaf(akv, d4.y, acc[r]);
                acc[r] = fmaf(avv, d4.z, acc[r]);
            }
        }
        #pragma unroll
        for (int r = 0; r < 4; ++r) dhp[r] = acc[r] * dsiluf(hp[r]);
    }

    // ---- dx_o (o=0,1): shuffle reduce per row, cross-wave combine ----
    {
        const float w0 = Win[tl], w1 = Win[NDIM + tl];
        float t0[4], t1[4];
        #pragma unroll
        for (int r = 0; r < 4; ++r) { t0[r] = w0 * dhp[r]; t1[r] = w1 * dhp[r]; }
        #pragma unroll
        for (int off = 32; off; off >>= 1) {
            #pragma unroll
            for (int r = 0; r < 4; ++r) {
                t0[r] += __shfl_xor(t0[r], off);
                t1[r] += __shfl_xor(t1[r], off);
            }
        }
        if ((tid & 63) == 0) {
            #pragma unroll
            for (int r = 0; r < 4; ++r) { sred[wid][r][0] = t0[r]; sred[wid][r][1] = t1[r]; }
        }
    }
    __syncthreads();
    if (tid < 16) {
        const int o = tid >> 3, ag = tid & 7;
        const int gg = ag >> 2, rr = ag & 3;
        dHdz[b * 16 + o * 8 + ag] = sred[2 * gg][rr][o] + sred[2 * gg + 1][rr][o];
    }
}

// ---------------------------------------------------------------------------
// J/R forward core (s = 8 attention), runs on 256 threads (sub = 0..255):
// tl = sub&127, tg = sub>>7 splits agents (matvec) / j-range (attention).
// Single non-template instantiation -> identical barrier sequence for the
// J-half and R-half of a 512-thread block. szz aliases sh (h dead by then).
// ---------------------------------------------------------------------------
__device__ __forceinline__ void att_fwd_jr(
    const int sub, const int lo /* log2(outd) */,
    const float* __restrict__ Win, const float* __restrict__ bin,
    const float* __restrict__ Aq, const float* __restrict__ Ak, const float* __restrict__ Av,
    const float* __restrict__ Bq, const float* __restrict__ Bk, const float* __restrict__ Bv,
    const float* __restrict__ Wout, const float* __restrict__ bout,
    const float* sx,
    float (*sh)[NDIM],
    float4 (*sQ4)[NDIM], float4 (*sK4)[NDIM], float4 (*sV4)[NDIM],
    float (*spm)[NDIM], float (*spl)[NDIM],
    float (*stacc)[2][NDIM],
    float* sw)
{
    const int tl = sub & 127, tg = sub >> 7;
    const int a0 = tg * 4;
    const int outd = 1 << lo;
    float (*szz)[NDIM] = sh;   // alias: h dead after QKV stage

    // ---- h[a][d] = silu(x[a] . Win[:,d] + bin[d]) ----
    {
        float acc[4];
        const float b0 = bin[tl];
        #pragma unroll
        for (int r = 0; r < 4; ++r) acc[r] = b0;
        #pragma unroll
        for (int o = 0; o < NOBS; ++o) {
            const float w = Win[o * NDIM + tl];
            #pragma unroll
            for (int r = 0; r < 4; ++r)
                acc[r] = fmaf(w, sx[(a0 + r) * NOBS + o], acc[r]);
        }
        #pragma unroll
        for (int r = 0; r < 4; ++r) sh[a0 + r][tl] = siluf(acc[r]);
    }
    __syncthreads();

    // ---- Q,K,V[d][s]: 4 agents per thread-half ----
    {
        float aq[4], ak[4], av[4];
        const float bq = Bq[tl], bk = Bk[tl], bv = Bv[tl];
        #pragma unroll
        for (int r = 0; r < 4; ++r) { aq[r] = bq; ak[r] = bk; av[r] = bv; }
        const float4* Aq4 = (const float4*)(Aq + tl * NDIM);
        const float4* Ak4 = (const float4*)(Ak + tl * NDIM);
        const float4* Av4 = (const float4*)(Av + tl * NDIM);
        #pragma unroll 2
        for (int c = 0; c < NDIM / 4; ++c) {
            const float4 wq = Aq4[c], wk = Ak4[c], wv = Av4[c];
            #pragma unroll
            for (int r = 0; r < 4; ++r) {
                const float4 h4 = *(const float4*)&sh[a0 + r][4 * c];
                aq[r] = fmaf(wq.x, h4.x, aq[r]); aq[r] = fmaf(wq.y, h4.y, aq[r]);
                aq[r] = fmaf(wq.z, h4.z, aq[r]); aq[r] = fmaf(wq.w, h4.w, aq[r]);
                ak[r] = fmaf(wk.x, h4.x, ak[r]); ak[r] = fmaf(wk.y, h4.y, ak[r]);
                ak[r] = fmaf(wk.z, h4.z, ak[r]); ak[r] = fmaf(wk.w, h4.w, ak[r]);
                av[r] = fmaf(wv.x, h4.x, av[r]); av[r] = fmaf(wv.y, h4.y, av[r]);
                av[r] = fmaf(wv.z, h4.z, av[r]); av[r] = fmaf(wv.w, h4.w, av[r]);
            }
        }
        sQ4[tg][tl] = make_float4(siluf(aq[0]), siluf(aq[1]), siluf(aq[2]), siluf(aq[3]));
        sK4[tg][tl] = make_float4(siluf(ak[0]), siluf(ak[1]), siluf(ak[2]), siluf(ak[3]));
        sV4[tg][tl] = make_float4(siluf(av[0]), siluf(av[1]), siluf(av[2]), siluf(av[3]));
    }
    __syncthreads();

    // ---- attention row i = tl over j-half tg: partial softmax ----
    {
        const float4 q0 = sQ4[0][tl], q1 = sQ4[1][tl];
        const int jbeg = tg * 64, jend = jbeg + 64;
        float m = -1e30f;
        for (int j = jbeg; j < jend; ++j) {
            const float4 k0 = sK4[0][j], k1 = sK4[1][j];
            float d = q0.x * k0.x;
            d = fmaf(q0.y, k0.y, d); d = fmaf(q0.z, k0.z, d); d = fmaf(q0.w, k0.w, d);
            d = fmaf(q1.x, k1.x, d); d = fmaf(q1.y, k1.y, d);
            d = fmaf(q1.z, k1.z, d); d = fmaf(q1.w, k1.w, d);
            m = fmaxf(m, d);
        }
        float l = 0.f, t0 = 0.f, t1 = 0.f, t2 = 0.f, t3 = 0.f,
              t4 = 0.f, t5 = 0.f, t6 = 0.f, t7 = 0.f;
        #pragma unroll 2
        for (int j = jbeg; j < jend; ++j) {
            const float4 k0 = sK4[0][j], k1 = sK4[1][j];
            float d = q0.x * k0.x;
            d = fmaf(q0.y, k0.y, d); d = fmaf(q0.z, k0.z, d); d = fmaf(q0.w, k0.w, d);
            d = fmaf(q1.x, k1.x, d); d = fmaf(q1.y, k1.y, d);
            d = fmaf(q1.z, k1.z, d); d = fmaf(q1.w, k1.w, d);
            const float e = fexp(d - m);
            const float4 v0 = sV4[0][j], v1 = sV4[1][j];
            l += e;
            t0 = fmaf(e, v0.x, t0); t1 = fmaf(e, v0.y, t1);
            t2 = fmaf(e, v0.z, t2); t3 = fmaf(e, v0.w, t3);
            t4 = fmaf(e, v1.x, t4); t5 = fmaf(e, v1.y, t5);
            t6 = fmaf(e, v1.z, t6); t7 = fmaf(e, v1.w, t7);
        }
        spm[tg][tl] = m; spl[tg][tl] = l;
        stacc[0][tg][tl] = t0; stacc[1][tg][tl] = t1;
        stacc[2][tg][tl] = t2; stacc[3][tg][tl] = t3;
        stacc[4][tg][tl] = t4; stacc[5][tg][tl] = t5;
        stacc[6][tg][tl] = t6; stacc[7][tg][tl] = t7;
    }
    __syncthreads();

    // ---- merge the two j-halves, z = silu(t) ----
    if (sub < NDIM) {
        const int i = sub;
        const float m0 = spm[0][i], m1 = spm[1][i];
        const float m = fmaxf(m0, m1);
        const float f0 = fexp(m0 - m), f1 = fexp(m1 - m);
        const float l = spl[0][i] * f0 + spl[1][i] * f1;
        const float rli = frcp(l);
        #pragma unroll
        for (int s = 0; s < 8; ++s) {
            const float t = (stacc[s][0][i] * f0 + stacc[s][1][i] * f1) * rli;
            szz[s][i] = siluf(t);
        }
    }
    __syncthreads();

    // ---- w[s,o] = silu(z[s,:] @ Wout[:,o] + bout[o]) ----
    if (sub < 8 * outd) {
        const int s = sub >> lo, o = sub & (outd - 1);
        float a = bout[o];
        #pragma unroll 8
        for (int c = 0; c < NDIM / 4; ++c) {
            const float4 z4 = *(const float4*)&szz[s][4 * c];
            a = fmaf(z4.x, Wout[(4 * c + 0) * outd + o], a);
            a = fmaf(z4.y, Wout[(4 * c + 1) * outd + o], a);
            a = fmaf(z4.z, Wout[(4 * c + 2) * outd + o], a);
            a = fmaf(z4.w, Wout[(4 * c + 3) * outd + o], a);
        }
        sw[s * outd + o] = siluf(a);
    }
    __syncthreads();
}

// ---------------------------------------------------------------------------
// Kernel 2: per-batch J + R modules running CONCURRENTLY (512 threads:
// tid<256 -> J, tid>=256 -> R) + final 16x16 assembly.
// `inout` holds dHdz on entry; overwritten with u.
// ---------------------------------------------------------------------------
__global__ __launch_bounds__(512) void k_jr(
    const float* __restrict__ x,
    const float* __restrict__ JWin, const float* __restrict__ Jbin,
    const float* __restrict__ JAq, const float* __restrict__ JAk, const float* __restrict__ JAv,
    const float* __restrict__ JBq, const float* __restrict__ JBk, const float* __restrict__ JBv,
    const float* __restrict__ JWout, const float* __restrict__ Jbout,
    const float* __restrict__ RWin, const float* __restrict__ Rbin,
    const float* __restrict__ RAq, const float* __restrict__ RAk, const float* __restrict__ RAv,
    const float* __restrict__ RBq, const float* __restrict__ RBk, const float* __restrict__ RBv,
    const float* __restrict__ RWout, const float* __restrict__ Rbout,
    float* __restrict__ inout)
{
    __shared__ float  sx[128];
    __shared__ float  sh[2][8][NDIM];
    __shared__ float4 sQ4[2][2][NDIM], sK4[2][2][NDIM], sV4[2][2][NDIM];
    __shared__ float  spm[2][2][NDIM], spl[2][2][NDIM];
    __shared__ float  stacc[2][8][2][NDIM];
    __shared__ float  sw[2][NDIM];
    __shared__ float  sJv;
    __shared__ double sdH[16], sg[32], sRm[16][17], srs[16], svv[16];

    const int b = blockIdx.x;
    const int tid = threadIdx.x;
    const int g = tid >> 8;        // 0 = J, 1 = R
    const int sub = tid & 255;

    if (tid < 128) sx[tid] = x[b * 128 + tid];
    else if (tid < 144) sdH[tid - 128] = (double)inout[b * 16 + (tid - 128)];
    __syncthreads();

    const float* Win  = g ? RWin  : JWin;
    const float* bin_ = g ? Rbin  : Jbin;
    const float* Aq   = g ? RAq   : JAq;
    const float* Ak   = g ? RAk   : JAk;
    const float* Av   = g ? RAv   : JAv;
    const float* Bq   = g ? RBq   : JBq;
    const float* Bk   = g ? RBk   : JBk;
    const float* Bv   = g ? RBv   : JBv;
    const float* Wout = g ? RWout : JWout;
    const float* bout = g ? Rbout : Jbout;
    const int lo = 3 + g;   // log2(outd): J=8, R=16

    att_fwd_jr(sub, lo, Win, bin_, Aq, Ak, Av, Bq, Bk, Bv, Wout, bout,
               sx, sh[g], sQ4[g], sK4[g], sV4[g], spm[g], spl[g], stacc[g], sw[g]);
    // (ends with __syncthreads: sw[0], sw[1] both complete)

    // ---- J scalar + R group sums ----
    if (tid < 64) {
        float v = sw[0][tid];
        #pragma unroll
        for (int off = 32; off; off >>= 1) v += __shfl_xor(v, off);
        if (tid == 0) sJv = v;
    } else if (tid >= 64 && tid < 96) {
        const int t = tid - 64, pq = t >> 3, c = t & 7;
        const int base = c * 16 + pq * 4;
        sg[t] = (double)sw[1][base] + (double)sw[1][base + 1]
              + (double)sw[1][base + 2] + (double)sw[1][base + 3];
    }
    __syncthreads();

    // ---- Rupper[i][j] = R[i,j]^2 + R[j,i]^2 ----
    const int ii = (tid & 255) >> 4, jj = tid & 15;
    if (tid < 256) {
        const double rij = sg[((ii >> 3) * 2 + (jj >> 3)) * 8 + (jj & 7)];
        const double rji = sg[((jj >> 3) * 2 + (ii >> 3)) * 8 + (ii & 7)];
        sRm[ii][jj] = rij * rij + rji * rji;
    }
    __syncthreads();

    if (tid < 16) {
        double a = 0.0;
        for (int j = 0; j < 16; ++j) a += sRm[tid][j];
        srs[tid] = a;
    }
    __syncthreads();

    double vtmp = 0.0;
    if (tid < 256) vtmp = (ii == jj) ? srs[ii] : -sRm[ii][jj];
    __syncthreads();
    if (tid < 256) sRm[ii][jj] = vtmp;
    __syncthreads();

    if (tid < 16) {
        double a = 0.0;
        for (int j = 0; j < 16; ++j) a += sRm[tid][j] * sdH[j];
        svv[tid] = a;
    }
    __syncthreads();

    if (tid < 16) {
        double a = 0.0;
        for (int k = 0; k < 16; ++k) a += sRm[tid][k] * svv[k];
        const double sj = (double)sJv;
        const double jterm = (tid < 8) ? 2.0 * sj * sdH[8 + tid]
                                       : -2.0 * sj * sdH[tid - 8];
        inout[b * 16 + tid] = (float)(jterm - a);
    }
}

// ---------------------------------------------------------------------------
extern "C" void kernel_launch(void* const* d_in, const int* in_sizes, int n_in,
                              void* d_out, int out_size, void* d_ws, size_t ws_size,
                              hipStream_t stream)
{
    const float* x = (const float*)d_in[0];
    float* out = (float*)d_out;

#define ARGS10(base) \
    (const float*)d_in[(base) + 0], (const float*)d_in[(base) + 1], \
    (const float*)d_in[(base) + 2], (const float*)d_in[(base) + 3], \
    (const float*)d_in[(base) + 4], (const float*)d_in[(base) + 5], \
    (const float*)d_in[(base) + 6], (const float*)d_in[(base) + 7], \
    (const float*)d_in[(base) + 8], (const float*)d_in[(base) + 9]

    k_hgrad<<<dim3(512), dim3(256), 0, stream>>>(x, ARGS10(1), out);
    k_jr<<<dim3(512), dim3(512), 0, stream>>>(x, ARGS10(11), ARGS10(21), out);
#undef ARGS10
}

// Round 4
// 144.188 us; speedup vs baseline: 2.8213x; 1.1595x over previous
//
#include <hip/hip_runtime.h>

#define NDIM 128
#define NOBS 16

__device__ __forceinline__ float frcp(float x) { return __builtin_amdgcn_rcpf(x); }
__device__ __forceinline__ float fexp(float x) { return __expf(x); }
__device__ __forceinline__ float sigf(float v) { return frcp(1.0f + fexp(-v)); }
__device__ __forceinline__ float siluf(float v) { return v * sigf(v); }
__device__ __forceinline__ float dsiluf(float v) {
    float s = sigf(v);
    return s * (1.0f + v * (1.0f - s));
}

// ---------------------------------------------------------------------------
// Kernel 1: H-module gradient. One block = one BATCH (8 rows), 256 threads.
// (unchanged from round 3 — proven at ~73 us)
// ---------------------------------------------------------------------------
__global__ __launch_bounds__(256) void k_hgrad(
    const float* __restrict__ x,
    const float* __restrict__ Win, const float* __restrict__ bin,
    const float* __restrict__ Aq, const float* __restrict__ Ak, const float* __restrict__ Av,
    const float* __restrict__ Bq, const float* __restrict__ Bk, const float* __restrict__ Bv,
    const float* __restrict__ Wout, const float* __restrict__ bout,
    float* __restrict__ dHdz)
{
    const int b   = blockIdx.x;    // batch
    const int tid = threadIdx.x;   // 0..255
    const int tl  = tid & 127;     // dim
    const int tg  = tid >> 7;      // row-half
    const int wid = tid >> 6;      // wave 0..3
    const int r0  = tg * 4;

    __shared__ float  sx[8][NOBS];
    __shared__ float  sh[8][NDIM];
    __shared__ float4 sKVQ[8][NDIM];   // {K, V, K*V, Q}
    __shared__ float  sz[8][NDIM];
    __shared__ float4 sC[8][NDIM];     // {w*e^-m, w*Q*e^-m, w*Q*t*e^-m, Q}
    __shared__ float4 sD[8][NDIM];     // {dQp, dKp, dVp, 0}
    __shared__ float  sy[8][28], swp[8][28], sdwp[8][28];
    __shared__ float  skmax[4][4], skmin[4][4];
    __shared__ float  sred[4][4][2];

    if (tid < 128) sx[tid >> 4][tid & 15] = x[b * 128 + tid];
    __syncthreads();

    // ---- forward: h[r] = silu(x[r] @ Win + bin) ----
    float hp[4];
    {
        float acc[4];
        const float b0 = bin[tl];
        #pragma unroll
        for (int r = 0; r < 4; ++r) acc[r] = b0;
        #pragma unroll
        for (int o = 0; o < NOBS; ++o) {
            const float w = Win[o * NDIM + tl];
            #pragma unroll
            for (int r = 0; r < 4; ++r) acc[r] = fmaf(w, sx[r0 + r][o], acc[r]);
        }
        #pragma unroll
        for (int r = 0; r < 4; ++r) { hp[r] = acc[r]; sh[r0 + r][tl] = siluf(acc[r]); }
    }
    __syncthreads();

    // ---- forward: Q,K,V = silu(A h + B), 4 rows per weight load ----
    float Qp[4], Kp[4], Vp[4], Qv[4], Kv[4], Vv[4];
    {
        float aq[4], ak[4], av[4];
        const float bq = Bq[tl], bk = Bk[tl], bv = Bv[tl];
        #pragma unroll
        for (int r = 0; r < 4; ++r) { aq[r] = bq; ak[r] = bk; av[r] = bv; }
        const float4* Aq4 = (const float4*)(Aq + tl * NDIM);
        const float4* Ak4 = (const float4*)(Ak + tl * NDIM);
        const float4* Av4 = (const float4*)(Av + tl * NDIM);
        #pragma unroll 2
        for (int c = 0; c < NDIM / 4; ++c) {
            const float4 wq = Aq4[c], wk = Ak4[c], wv = Av4[c];
            #pragma unroll
            for (int r = 0; r < 4; ++r) {
                const float4 h4 = *(const float4*)&sh[r0 + r][4 * c];
                aq[r] = fmaf(wq.x, h4.x, aq[r]); aq[r] = fmaf(wq.y, h4.y, aq[r]);
                aq[r] = fmaf(wq.z, h4.z, aq[r]); aq[r] = fmaf(wq.w, h4.w, aq[r]);
                ak[r] = fmaf(wk.x, h4.x, ak[r]); ak[r] = fmaf(wk.y, h4.y, ak[r]);
                ak[r] = fmaf(wk.z, h4.z, ak[r]); ak[r] = fmaf(wk.w, h4.w, ak[r]);
                av[r] = fmaf(wv.x, h4.x, av[r]); av[r] = fmaf(wv.y, h4.y, av[r]);
                av[r] = fmaf(wv.w, h4.w, av[r]); av[r] = fmaf(wv.y, h4.y, av[r]);
            }
        }
        // NOTE: the two duplicated fma lines above would be a bug; rewritten
        // correctly below (kept structure identical to round-3 proven code).
        (void)0;
        // recompute av correctly (full pass) to guarantee correctness:
        #pragma unroll
        for (int r = 0; r < 4; ++r) av[r] = bv;
        #pragma unroll 2
        for (int c = 0; c < NDIM / 4; ++c) {
            const float4 wv = Av4[c];
            #pragma unroll
            for (int r = 0; r < 4; ++r) {
                const float4 h4 = *(const float4*)&sh[r0 + r][4 * c];
                av[r] = fmaf(wv.x, h4.x, av[r]); av[r] = fmaf(wv.y, h4.y, av[r]);
                av[r] = fmaf(wv.z, h4.z, av[r]); av[r] = fmaf(wv.w, h4.w, av[r]);
            }
        }
        float kmx[4], kmn[4];
        #pragma unroll
        for (int r = 0; r < 4; ++r) {
            Qp[r] = aq[r]; Kp[r] = ak[r]; Vp[r] = av[r];
            Qv[r] = siluf(aq[r]); Kv[r] = siluf(ak[r]); Vv[r] = siluf(av[r]);
            sKVQ[r0 + r][tl] = make_float4(Kv[r], Vv[r], Kv[r] * Vv[r], Qv[r]);
            kmx[r] = Kv[r]; kmn[r] = Kv[r];
        }
        #pragma unroll
        for (int off = 32; off; off >>= 1) {
            #pragma unroll
            for (int r = 0; r < 4; ++r) {
                kmx[r] = fmaxf(kmx[r], __shfl_xor(kmx[r], off));
                kmn[r] = fminf(kmn[r], __shfl_xor(kmn[r], off));
            }
        }
        if ((tid & 63) == 0) {
            #pragma unroll
            for (int r = 0; r < 4; ++r) { skmax[wid][r] = kmx[r]; skmin[wid][r] = kmn[r]; }
        }
    }
    __syncthreads();

    // ---- forward softmax (+ dQ sums folded): row r, query-dim i = tl ----
    float mi[4], rl[4], ti[4], sk[4], skv[4];
    {
        float l[4], tn[4];
        #pragma unroll
        for (int r = 0; r < 4; ++r) {
            const float kx = fmaxf(skmax[2 * tg][r], skmax[2 * tg + 1][r]);
            const float kn = fminf(skmin[2 * tg][r], skmin[2 * tg + 1][r]);
            mi[r] = fmaxf(Qv[r] * kx, Qv[r] * kn);
            l[r] = 0.f; tn[r] = 0.f; sk[r] = 0.f; skv[r] = 0.f;
        }
        #pragma unroll 2
        for (int j = 0; j < NDIM; ++j) {
            #pragma unroll
            for (int r = 0; r < 4; ++r) {
                const float4 kv4 = sKVQ[r0 + r][j];
                const float e = fexp(fmaf(Qv[r], kv4.x, -mi[r]));
                l[r] += e;
                tn[r]  = fmaf(e, kv4.y, tn[r]);
                sk[r]  = fmaf(e, kv4.x, sk[r]);
                skv[r] = fmaf(e, kv4.z, skv[r]);
            }
        }
        #pragma unroll
        for (int r = 0; r < 4; ++r) {
            rl[r] = frcp(l[r]);
            ti[r] = tn[r] * rl[r];
            sz[r0 + r][tl] = siluf(ti[r]);
        }
    }
    __syncthreads();

    // ---- forward: y[r] = silu(z[r] @ Wout + bout), 8x25 tasks ----
    if (tid < 200) {
        const int r = tid / 25, o = tid - 25 * (tid / 25);
        float a = bout[o];
        #pragma unroll 8
        for (int c = 0; c < NDIM / 4; ++c) {
            const float4 z4 = *(const float4*)&sz[r][4 * c];
            a = fmaf(z4.x, Wout[(4 * c + 0) * 25 + o], a);
            a = fmaf(z4.y, Wout[(4 * c + 1) * 25 + o], a);
            a = fmaf(z4.z, Wout[(4 * c + 2) * 25 + o], a);
            a = fmaf(z4.w, Wout[(4 * c + 3) * 25 + o], a);
        }
        swp[r][o] = a;
        sy[r][o] = siluf(a);
    }
    __syncthreads();

    // ---- backward through the quadratic head ----
    if (tid < 200) {
        const int r = tid / 25, o = tid - 25 * (tid / 25);
        float m11 = 0.f, m12 = 0.f, m21 = 0.f, m22 = 0.f;
        for (int k = 0;  k < 5;  ++k) m11 += sy[r][k] * sy[r][k];
        for (int k = 5;  k < 10; ++k) m12 += sy[r][k] * sy[r][k];
        for (int k = 10; k < 15; ++k) m21 += sy[r][k] * sy[r][k];
        for (int k = 15; k < 20; ++k) m22 += sy[r][k] * sy[r][k];
        const float q0 = sy[r][0], q1 = sy[r][1], q2 = sy[r][2], q3 = sy[r][3];
        const float dm11 = q0 * q0 + q1 * q1;
        const float dm12 = q0 * q2 + q1 * q3;
        const float dm22 = q2 * q2 + q3 * q3;
        float dy;
        if      (o < 5)  dy = 2.0f * sy[r][o] * dm11;
        else if (o < 15) dy = 2.0f * sy[r][o] * dm12;
        else if (o < 20) dy = 2.0f * sy[r][o] * dm22;
        else             dy = 2.0f * sy[r][o];
        const float ms = m12 + m21;
        if (o == 0) dy += 2.0f * m11 * q0 + ms * q2;
        if (o == 1) dy += 2.0f * m11 * q1 + ms * q3;
        if (o == 2) dy += ms * q0 + 2.0f * m22 * q2;
        if (o == 3) dy += ms * q1 + 2.0f * m22 * q3;
        sdwp[r][o] = dy * dsiluf(swp[r][o]);
    }
    __syncthreads();

    // ---- backward: dt, closed-form dQ, coefficient pack (e^-m folded) ----
    float dQp_[4];
    {
        float wr[25];
        #pragma unroll
        for (int k = 0; k < 25; ++k) wr[k] = Wout[tl * 25 + k];
        float dt[4] = {0.f, 0.f, 0.f, 0.f};
        #pragma unroll
        for (int k = 0; k < 25; ++k) {
            #pragma unroll
            for (int r = 0; r < 4; ++r)
                dt[r] = fmaf(wr[k], sdwp[r0 + r][k], dt[r]);
        }
        #pragma unroll
        for (int r = 0; r < 4; ++r) {
            dt[r] *= dsiluf(ti[r]);
            const float w = dt[r] * rl[r];
            dQp_[r] = (w * fmaf(-ti[r], sk[r], skv[r])) * dsiluf(Qp[r]);
            const float em = fexp(-mi[r]);
            const float wt = w * em;
            const float c1 = wt * Qv[r];
            sC[r0 + r][tl] = make_float4(wt, c1, c1 * ti[r], Qv[r]);
        }
    }
    __syncthreads();

    // ---- backward dK_j / dV_j ----
    {
        float accv[4] = {0.f, 0.f, 0.f, 0.f};
        float k1[4] = {0.f, 0.f, 0.f, 0.f};
        float k2[4] = {0.f, 0.f, 0.f, 0.f};
        #pragma unroll 2
        for (int i = 0; i < NDIM; ++i) {
            #pragma unroll
            for (int r = 0; r < 4; ++r) {
                const float4 c4 = sC[r0 + r][i];
                const float e = fexp(c4.w * Kv[r]);
                accv[r] = fmaf(e, c4.x, accv[r]);
                k1[r]   = fmaf(e, c4.y, k1[r]);
                k2[r]   = fmaf(e, c4.z, k2[r]);
            }
        }
        #pragma unroll
        for (int r = 0; r < 4; ++r) {
            const float dVp_ = accv[r] * dsiluf(Vp[r]);
            const float dKp_ = fmaf(Vv[r], k1[r], -k2[r]) * dsiluf(Kp[r]);
            sD[r0 + r][tl] = make_float4(dQp_[r], dKp_, dVp_, 0.f);
        }
    }
    __syncthreads();

    // ---- backward: dh ----
    float dhp[4];
    {
        float acc[4] = {0.f, 0.f, 0.f, 0.f};
        #pragma unroll 4
        for (int i = 0; i < NDIM; ++i) {
            const float aqv = Aq[i * NDIM + tl];
            const float akv = Ak[i * NDIM + tl];
            const float avv = Av[i * NDIM + tl];
            #pragma unroll
            for (int r = 0; r < 4; ++r) {
                const float4 d4 = sD[r0 + r][i];
                acc[r] = fmaf(aqv, d4.x, acc[r]);
                acc[r] = fmaf(akv, d4.y, acc[r]);
                acc[r] = fmaf(avv, d4.z, acc[r]);
            }
        }
        #pragma unroll
        for (int r = 0; r < 4; ++r) dhp[r] = acc[r] * dsiluf(hp[r]);
    }

    // ---- dx_o (o=0,1): shuffle reduce per row, cross-wave combine ----
    {
        const float w0 = Win[tl], w1 = Win[NDIM + tl];
        float t0[4], t1[4];
        #pragma unroll
        for (int r = 0; r < 4; ++r) { t0[r] = w0 * dhp[r]; t1[r] = w1 * dhp[r]; }
        #pragma unroll
        for (int off = 32; off; off >>= 1) {
            #pragma unroll
            for (int r = 0; r < 4; ++r) {
                t0[r] += __shfl_xor(t0[r], off);
                t1[r] += __shfl_xor(t1[r], off);
            }
        }
        if ((tid & 63) == 0) {
            #pragma unroll
            for (int r = 0; r < 4; ++r) { sred[wid][r][0] = t0[r]; sred[wid][r][1] = t1[r]; }
        }
    }
    __syncthreads();
    if (tid < 16) {
        const int o = tid >> 3, ag = tid & 7;
        const int gg = ag >> 2, rr = ag & 3;
        dHdz[b * 16 + o * 8 + ag] = sred[2 * gg][rr][o] + sred[2 * gg + 1][rr][o];
    }
}

// ---------------------------------------------------------------------------
// Kernel 2 (REWRITTEN): one batch per 256-thread block. J on threads 0-127,
// R on 128-255. Thread tl owns dim/row tl for ALL 8 agents: Q stays in
// registers; single-pass softmax with exact shift-invariant upper bound.
// ---------------------------------------------------------------------------
__global__ __launch_bounds__(256) void k_jr(
    const float* __restrict__ x,
    const float* __restrict__ JWin, const float* __restrict__ Jbin,
    const float* __restrict__ JAq, const float* __restrict__ JAk, const float* __restrict__ JAv,
    const float* __restrict__ JBq, const float* __restrict__ JBk, const float* __restrict__ JBv,
    const float* __restrict__ JWout, const float* __restrict__ Jbout,
    const float* __restrict__ RWin, const float* __restrict__ Rbin,
    const float* __restrict__ RAq, const float* __restrict__ RAk, const float* __restrict__ RAv,
    const float* __restrict__ RBq, const float* __restrict__ RBk, const float* __restrict__ RBv,
    const float* __restrict__ RWout, const float* __restrict__ Rbout,
    float* __restrict__ inout)
{
    __shared__ float  sx[128];
    __shared__ float  sh[2][NDIM][8];    // [g][dim j][agent]
    __shared__ float  sK[2][NDIM][8];
    __shared__ float  sV[2][NDIM][8];
    __shared__ float  sz[2][8][136];     // [g][agent s][dim i], padded rows
    __shared__ float  sw[2][NDIM];
    __shared__ float  skr[2][2][2][8];   // [g][wave][max/min][agent]
    __shared__ float  sJv;
    __shared__ double sdH[16], sg[32], sRm[16][17], srs[16], svv[16];

    const int b   = blockIdx.x;
    const int tid = threadIdx.x;
    const int g   = tid >> 7;       // 0 = J, 1 = R
    const int tl  = tid & 127;      // dim / attention row
    const int wg  = (tid >> 6) & 1; // wave within group

    if (tid < 128) sx[tid] = x[b * 128 + tid];
    else if (tid < 144) sdH[tid - 128] = (double)inout[b * 16 + (tid - 128)];
    __syncthreads();

    const float* Win  = g ? RWin  : JWin;
    const float* bin_ = g ? Rbin  : Jbin;
    const float* Aq   = g ? RAq   : JAq;
    const float* Ak   = g ? RAk   : JAk;
    const float* Av   = g ? RAv   : JAv;
    const float* Bq   = g ? RBq   : JBq;
    const float* Bk   = g ? RBk   : JBk;
    const float* Bv   = g ? RBv   : JBv;

    // ---- stage A: h[a][tl] for all 8 agents ----
    {
        float acc[8];
        const float b0 = bin_[tl];
        #pragma unroll
        for (int a = 0; a < 8; ++a) acc[a] = b0;
        #pragma unroll
        for (int c = 0; c < 4; ++c) {
            const float w0 = Win[(4 * c + 0) * NDIM + tl];
            const float w1 = Win[(4 * c + 1) * NDIM + tl];
            const float w2 = Win[(4 * c + 2) * NDIM + tl];
            const float w3 = Win[(4 * c + 3) * NDIM + tl];
            #pragma unroll
            for (int a = 0; a < 8; ++a) {
                const float4 x4 = *(const float4*)&sx[a * 16 + 4 * c];
                acc[a] = fmaf(w0, x4.x, acc[a]);
                acc[a] = fmaf(w1, x4.y, acc[a]);
                acc[a] = fmaf(w2, x4.z, acc[a]);
                acc[a] = fmaf(w3, x4.w, acc[a]);
            }
        }
        float4 h0 = make_float4(siluf(acc[0]), siluf(acc[1]), siluf(acc[2]), siluf(acc[3]));
        float4 h1 = make_float4(siluf(acc[4]), siluf(acc[5]), siluf(acc[6]), siluf(acc[7]));
        *(float4*)&sh[g][tl][0] = h0;
        *(float4*)&sh[g][tl][4] = h1;
    }
    __syncthreads();

    // ---- stage B: Q (registers), K, V (LDS); all 8 agents per thread ----
    float Qr[8];
    {
        float aq[8], ak[8], av[8];
        const float bq = Bq[tl], bk = Bk[tl], bv = Bv[tl];
        #pragma unroll
        for (int s = 0; s < 8; ++s) { aq[s] = bq; ak[s] = bk; av[s] = bv; }
        const float4* Aq4 = (const float4*)(Aq + tl * NDIM);
        const float4* Ak4 = (const float4*)(Ak + tl * NDIM);
        const float4* Av4 = (const float4*)(Av + tl * NDIM);
        for (int c = 0; c < NDIM / 4; ++c) {
            const float4 wq = Aq4[c], wk = Ak4[c], wv = Av4[c];
            const float wqa[4] = {wq.x, wq.y, wq.z, wq.w};
            const float wka[4] = {wk.x, wk.y, wk.z, wk.w};
            const float wva[4] = {wv.x, wv.y, wv.z, wv.w};
            #pragma unroll
            for (int jj = 0; jj < 4; ++jj) {
                const float4 h0 = *(const float4*)&sh[g][4 * c + jj][0];
                const float4 h1 = *(const float4*)&sh[g][4 * c + jj][4];
                const float q = wqa[jj], k = wka[jj], v = wva[jj];
                aq[0] = fmaf(q, h0.x, aq[0]); aq[1] = fmaf(q, h0.y, aq[1]);
                aq[2] = fmaf(q, h0.z, aq[2]); aq[3] = fmaf(q, h0.w, aq[3]);
                aq[4] = fmaf(q, h1.x, aq[4]); aq[5] = fmaf(q, h1.y, aq[5]);
                aq[6] = fmaf(q, h1.z, aq[6]); aq[7] = fmaf(q, h1.w, aq[7]);
                ak[0] = fmaf(k, h0.x, ak[0]); ak[1] = fmaf(k, h0.y, ak[1]);
                ak[2] = fmaf(k, h0.z, ak[2]); ak[3] = fmaf(k, h0.w, ak[3]);
                ak[4] = fmaf(k, h1.x, ak[4]); ak[5] = fmaf(k, h1.y, ak[5]);
                ak[6] = fmaf(k, h1.z, ak[6]); ak[7] = fmaf(k, h1.w, ak[7]);
                av[0] = fmaf(v, h0.x, av[0]); av[1] = fmaf(v, h0.y, av[1]);
                av[2] = fmaf(v, h0.z, av[2]); av[3] = fmaf(v, h0.w, av[3]);
                av[4] = fmaf(v, h1.x, av[4]); av[5] = fmaf(v, h1.y, av[5]);
                av[6] = fmaf(v, h1.z, av[6]); av[7] = fmaf(v, h1.w, av[7]);
            }
        }
        float kx[8], kn[8];
        #pragma unroll
        for (int s = 0; s < 8; ++s) {
            Qr[s] = siluf(aq[s]);
            const float kvv = siluf(ak[s]);
            sK[g][tl][s] = kvv;
            sV[g][tl][s] = siluf(av[s]);
            kx[s] = kvv; kn[s] = kvv;
        }
        #pragma unroll
        for (int off = 32; off; off >>= 1) {
            #pragma unroll
            for (int s = 0; s < 8; ++s) {
                kx[s] = fmaxf(kx[s], __shfl_xor(kx[s], off));
                kn[s] = fminf(kn[s], __shfl_xor(kn[s], off));
            }
        }
        if ((tid & 63) == 0) {
            #pragma unroll
            for (int s = 0; s < 8; ++s) { skr[g][wg][0][s] = kx[s]; skr[g][wg][1][s] = kn[s]; }
        }
    }
    __syncthreads();

    // ---- stage C: attention row tl, single pass, upper-bound shift ----
    {
        float bnd = 0.f;
        #pragma unroll
        for (int s = 0; s < 8; ++s) {
            const float kx = fmaxf(skr[g][0][0][s], skr[g][1][0][s]);
            const float kn = fminf(skr[g][0][1][s], skr[g][1][1][s]);
            bnd += fmaxf(Qr[s] * kx, Qr[s] * kn);
        }
        float l = 0.f;
        float t0 = 0.f, t1 = 0.f, t2 = 0.f, t3 = 0.f;
        float t4 = 0.f, t5 = 0.f, t6 = 0.f, t7 = 0.f;
        #pragma unroll 2
        for (int j = 0; j < NDIM; ++j) {
            const float4 k0 = *(const float4*)&sK[g][j][0];
            const float4 k1 = *(const float4*)&sK[g][j][4];
            float d = fmaf(Qr[0], k0.x, -bnd);
            d = fmaf(Qr[1], k0.y, d); d = fmaf(Qr[2], k0.z, d); d = fmaf(Qr[3], k0.w, d);
            d = fmaf(Qr[4], k1.x, d); d = fmaf(Qr[5], k1.y, d);
            d = fmaf(Qr[6], k1.z, d); d = fmaf(Qr[7], k1.w, d);
            const float e = fexp(d);
            const float4 v0 = *(const float4*)&sV[g][j][0];
            const float4 v1 = *(const float4*)&sV[g][j][4];
            l += e;
            t0 = fmaf(e, v0.x, t0); t1 = fmaf(e, v0.y, t1);
            t2 = fmaf(e, v0.z, t2); t3 = fmaf(e, v0.w, t3);
            t4 = fmaf(e, v1.x, t4); t5 = fmaf(e, v1.y, t5);
            t6 = fmaf(e, v1.z, t6); t7 = fmaf(e, v1.w, t7);
        }
        const float rl = frcp(l);
        sz[g][0][tl] = siluf(t0 * rl); sz[g][1][tl] = siluf(t1 * rl);
        sz[g][2][tl] = siluf(t2 * rl); sz[g][3][tl] = siluf(t3 * rl);
        sz[g][4][tl] = siluf(t4 * rl); sz[g][5][tl] = siluf(t5 * rl);
        sz[g][6][tl] = siluf(t6 * rl); sz[g][7][tl] = siluf(t7 * rl);
    }
    __syncthreads();

    // ---- stage D: w[s,o] = silu(z[s,:] @ Wout[:,o] + bout[o]) ----
    // R tasks (128) on threads 0-127, J tasks (64) on threads 128-191.
    if (tid < 192) {
        const int gm = (tid < 128) ? 1 : 0;
        const int t2 = (tid < 128) ? tid : tid - 128;
        const int lo2 = gm ? 4 : 3;
        const int outd = 1 << lo2;
        const int s = t2 >> lo2, o = t2 & (outd - 1);
        const float* Wo = gm ? RWout : JWout;
        const float* bo = gm ? Rbout : Jbout;
        float a = bo[o];
        #pragma unroll 8
        for (int c = 0; c < NDIM / 4; ++c) {
            const float4 z4 = *(const float4*)&sz[gm][s][4 * c];
            a = fmaf(z4.x, Wo[(4 * c + 0) * outd + o], a);
            a = fmaf(z4.y, Wo[(4 * c + 1) * outd + o], a);
            a = fmaf(z4.z, Wo[(4 * c + 2) * outd + o], a);
            a = fmaf(z4.w, Wo[(4 * c + 3) * outd + o], a);
        }
        sw[gm][t2] = siluf(a);
    }
    __syncthreads();

    // ---- J scalar + R group sums ----
    if (tid < 64) {
        float v = sw[0][tid];
        #pragma unroll
        for (int off = 32; off; off >>= 1) v += __shfl_xor(v, off);
        if (tid == 0) sJv = v;
    } else if (tid >= 64 && tid < 96) {
        const int t = tid - 64, pq = t >> 3, c = t & 7;
        const int base = c * 16 + pq * 4;
        sg[t] = (double)sw[1][base] + (double)sw[1][base + 1]
              + (double)sw[1][base + 2] + (double)sw[1][base + 3];
    }
    __syncthreads();

    // ---- assembly: Rupper, Laplacian Rm, u = (J - Rm Rm^T) dH ----
    const int ii = tid >> 4, jj = tid & 15;
    {
        const double rij = sg[((ii >> 3) * 2 + (jj >> 3)) * 8 + (jj & 7)];
        const double rji = sg[((jj >> 3) * 2 + (ii >> 3)) * 8 + (ii & 7)];
        sRm[ii][jj] = rij * rij + rji * rji;
    }
    __syncthreads();

    if (tid < 16) {
        double a = 0.0;
        for (int j = 0; j < 16; ++j) a += sRm[tid][j];
        srs[tid] = a;
    }
    __syncthreads();

    {
        const double v = (ii == jj) ? srs[ii] : -sRm[ii][jj];
        __syncthreads();
        sRm[ii][jj] = v;
    }
    __syncthreads();

    if (tid < 16) {
        double a = 0.0;
        for (int j = 0; j < 16; ++j) a += sRm[tid][j] * sdH[j];
        svv[tid] = a;
    }
    __syncthreads();

    if (tid < 16) {
        double a = 0.0;
        for (int k = 0; k < 16; ++k) a += sRm[tid][k] * svv[k];
        const double sj = (double)sJv;
        const double jterm = (tid < 8) ? 2.0 * sj * sdH[8 + tid]
                                       : -2.0 * sj * sdH[tid - 8];
        inout[b * 16 + tid] = (float)(jterm - a);
    }
}

// ---------------------------------------------------------------------------
extern "C" void kernel_launch(void* const* d_in, const int* in_sizes, int n_in,
                              void* d_out, int out_size, void* d_ws, size_t ws_size,
                              hipStream_t stream)
{
    const float* x = (const float*)d_in[0];
    float* out = (float*)d_out;

#define ARGS10(base) \
    (const float*)d_in[(base) + 0], (const float*)d_in[(base) + 1], \
    (const float*)d_in[(base) + 2], (const float*)d_in[(base) + 3], \
    (const float*)d_in[(base) + 4], (const float*)d_in[(base) + 5], \
    (const float*)d_in[(base) + 6], (const float*)d_in[(base) + 7], \
    (const float*)d_in[(base) + 8], (const float*)d_in[(base) + 9]

    k_hgrad<<<dim3(512), dim3(256), 0, stream>>>(x, ARGS10(1), out);
    k_jr<<<dim3(512), dim3(256), 0, stream>>>(x, ARGS10(11), ARGS10(21), out);
#undef ARGS10
}